// Round 1
// baseline (287.743 us; speedup 1.0000x reference)
//
#include <hip/hip_runtime.h>

#define BB 1024
#define VV 50000
#define TT 50

__global__ __launch_bounds__(256) void listmle_tail_kernel(
    const float* __restrict__ output,
    const int*   __restrict__ target,
    const int*   __restrict__ tails,
    const int*   __restrict__ tail_len,
    float*       __restrict__ out)
{
    const int b   = blockIdx.x;
    const int tid = threadIdx.x;
    const float* __restrict__ row = output + (size_t)b * VV;

    // ---- Phase 1: sum(exp(row)) over V=50000, coalesced float4 stream ----
    const float4* __restrict__ row4 = (const float4*)row;
    const int n4 = VV / 4;  // 12500, V divisible by 4
    float sum = 0.0f;
    for (int i = tid; i < n4; i += 256) {
        float4 v = row4[i];
        sum += __expf(v.x) + __expf(v.y) + __expf(v.z) + __expf(v.w);
    }

    // wave (64-lane) shuffle reduction
    #pragma unroll
    for (int off = 32; off > 0; off >>= 1)
        sum += __shfl_down(sum, off, 64);

    __shared__ float wave_sums[4];
    __shared__ float total_exp_s;
    __shared__ float es_s[TT];   // exp of tail scores
    __shared__ float s_s[TT];    // tail scores

    const int lane = tid & 63;
    const int wave = tid >> 6;
    if (lane == 0) wave_sums[wave] = sum;

    // ---- Phase 2: gather tail scores in parallel ----
    const int L = tail_len[b];
    if (tid < TT) {
        if (tid < L) {
            int idx = tails[b * TT + tid];
            float sv = row[idx];
            s_s[tid]  = sv;
            es_s[tid] = __expf(sv);
        } else {
            s_s[tid]  = 0.0f;
            es_s[tid] = 0.0f;
        }
    }
    __syncthreads();

    if (tid == 0) {
        total_exp_s = wave_sums[0] + wave_sums[1] + wave_sums[2] + wave_sums[3];
    }
    __syncthreads();

    // ---- Phase 3: serial tail scan (T=50) on thread 0 ----
    if (tid == 0) {
        const float total_exp = total_exp_s;
        const float ts = row[target[b]];
        const float log_pl = ts - __logf(total_exp);

        float above = 0.0f, sum_es = 0.0f;
        for (int j = 0; j < L; ++j) {
            above  += s_s[j];
            sum_es += es_s[j];
        }
        const float others = total_exp - __expf(ts) - sum_es;

        // reversed cumsum of es, log each prefix
        float run = 0.0f, below = 0.0f;
        for (int k = L - 1; k >= 0; --k) {
            run += es_s[k];
            below += __logf(run + others);
        }
        const float tail_term = (L > 0) ? (above - below) : 0.0f;
        out[b] = -(log_pl + tail_term);
    }
}

extern "C" void kernel_launch(void* const* d_in, const int* in_sizes, int n_in,
                              void* d_out, int out_size, void* d_ws, size_t ws_size,
                              hipStream_t stream) {
    const float* output   = (const float*)d_in[0];
    const int*   target   = (const int*)d_in[1];
    const int*   tails    = (const int*)d_in[2];
    const int*   tail_len = (const int*)d_in[3];
    float*       out      = (float*)d_out;

    listmle_tail_kernel<<<BB, 256, 0, stream>>>(output, target, tails, tail_len, out);
}

// Round 2
// 286.818 us; speedup vs baseline: 1.0032x; 1.0032x over previous
//
#include <hip/hip_runtime.h>

#define BB 1024
#define VV 50000
#define TT 50
// Each row (50000 floats = 12500 float4) split into 4 quarter-row blocks of
// 3125 float4 each. 3125 = 12*256 + 53.
#define Q4 3125

// ---- Kernel A: partial sum(exp(row_quarter)) -> partials[4096] ----
// 4096 blocks x 256 threads. 12 fully-unrolled float4 loads per thread issue
// back-to-back (max loads in flight), 4 independent accumulators for ILP.
__global__ __launch_bounds__(256) void expsum_partial_kernel(
    const float* __restrict__ output,
    float*       __restrict__ partials)
{
    const int blk = blockIdx.x;
    const int row = blk >> 2;
    const int q   = blk & 3;
    const int tid = threadIdx.x;
    const float4* __restrict__ p =
        (const float4*)(output + (size_t)row * VV) + q * Q4;

    float4 v[12];
    #pragma unroll
    for (int u = 0; u < 12; ++u) v[u] = p[tid + 256 * u];
    const bool has_tail = tid < (Q4 - 12 * 256);   // tid < 53
    float4 vt = make_float4(0.f, 0.f, 0.f, 0.f);
    if (has_tail) vt = p[tid + 256 * 12];

    float s0 = 0.f, s1 = 0.f, s2 = 0.f, s3 = 0.f;
    #pragma unroll
    for (int u = 0; u < 12; ++u) {
        s0 += __expf(v[u].x);
        s1 += __expf(v[u].y);
        s2 += __expf(v[u].z);
        s3 += __expf(v[u].w);
    }
    if (has_tail) {
        s0 += __expf(vt.x);
        s1 += __expf(vt.y);
        s2 += __expf(vt.z);
        s3 += __expf(vt.w);
    }
    float sum = (s0 + s1) + (s2 + s3);

    #pragma unroll
    for (int off = 32; off > 0; off >>= 1)
        sum += __shfl_down(sum, off, 64);

    __shared__ float wsum[4];
    const int lane = tid & 63;
    const int wave = tid >> 6;
    if (lane == 0) wsum[wave] = sum;
    __syncthreads();
    if (tid == 0)
        partials[blk] = (wsum[0] + wsum[1]) + (wsum[2] + wsum[3]);
}

// ---- Kernel B: tail computation, one 64-thread block per row ----
// Lanes 0..49 gather tail scores in parallel (one memory round-trip),
// lane 0 runs the inherently-serial reversed cumsum/log scan from LDS.
__global__ __launch_bounds__(64) void tail_kernel(
    const float* __restrict__ output,
    const int*   __restrict__ target,
    const int*   __restrict__ tails,
    const int*   __restrict__ tail_len,
    const float* __restrict__ partials,
    float*       __restrict__ out)
{
    const int r   = blockIdx.x;
    const int tid = threadIdx.x;
    const float* __restrict__ row = output + (size_t)r * VV;

    __shared__ float s_s[TT];
    __shared__ float es_s[TT];

    const int L = tail_len[r];
    if (tid < TT) {
        float sv = 0.f, ev = 0.f;
        if (tid < L) {
            sv = row[tails[r * TT + tid]];
            ev = __expf(sv);
        }
        s_s[tid]  = sv;
        es_s[tid] = ev;
    }
    __syncthreads();

    if (tid == 0) {
        const float total =
            (partials[4 * r] + partials[4 * r + 1]) +
            (partials[4 * r + 2] + partials[4 * r + 3]);
        const float ts = row[target[r]];
        const float log_pl = ts - __logf(total);

        float above = 0.f, sum_es = 0.f;
        for (int j = 0; j < L; ++j) {
            above  += s_s[j];
            sum_es += es_s[j];
        }
        const float others = total - __expf(ts) - sum_es;

        float run = 0.f, below = 0.f;
        for (int k = L - 1; k >= 0; --k) {
            run += es_s[k];
            below += __logf(run + others);
        }
        const float tail_term = (L > 0) ? (above - below) : 0.f;
        out[r] = -(log_pl + tail_term);
    }
}

extern "C" void kernel_launch(void* const* d_in, const int* in_sizes, int n_in,
                              void* d_out, int out_size, void* d_ws, size_t ws_size,
                              hipStream_t stream) {
    const float* output   = (const float*)d_in[0];
    const int*   target   = (const int*)d_in[1];
    const int*   tails    = (const int*)d_in[2];
    const int*   tail_len = (const int*)d_in[3];
    float*       out      = (float*)d_out;
    float*       partials = (float*)d_ws;   // 4096 floats, fully overwritten by kernel A

    expsum_partial_kernel<<<BB * 4, 256, 0, stream>>>(output, partials);
    tail_kernel<<<BB, 64, 0, stream>>>(output, target, tails, tail_len, partials, out);
}

// Round 3
// 282.857 us; speedup vs baseline: 1.0173x; 1.0140x over previous
//
#include <hip/hip_runtime.h>

#define BB 1024
#define VV 50000
#define TT 50
// One 1024-thread block per row. Row = 12500 float4 = 12*1024 + 212.
#define NTH 1024
#define N4  12500
#define FULL_ITERS 12
#define REM (N4 - FULL_ITERS * NTH)   // 212

__global__ __launch_bounds__(NTH) void listmle_fused_kernel(
    const float* __restrict__ output,
    const int*   __restrict__ target,
    const int*   __restrict__ tails,
    const int*   __restrict__ tail_len,
    float*       __restrict__ out)
{
    const int r   = blockIdx.x;
    const int tid = threadIdx.x;
    const float* __restrict__ row = output + (size_t)r * VV;
    const float4* __restrict__ p = (const float4*)row;

    // ---- stream the row: 12 unrolled float4 loads per thread, back-to-back ----
    float4 v[FULL_ITERS];
    #pragma unroll
    for (int u = 0; u < FULL_ITERS; ++u) v[u] = p[tid + NTH * u];
    const bool has_rem = tid < REM;
    float4 vt = make_float4(0.f, 0.f, 0.f, 0.f);
    if (has_rem) vt = p[tid + NTH * FULL_ITERS];

    float s0 = 0.f, s1 = 0.f, s2 = 0.f, s3 = 0.f;
    #pragma unroll
    for (int u = 0; u < FULL_ITERS; ++u) {
        s0 += __expf(v[u].x);
        s1 += __expf(v[u].y);
        s2 += __expf(v[u].z);
        s3 += __expf(v[u].w);
    }
    if (has_rem) {
        s0 += __expf(vt.x);
        s1 += __expf(vt.y);
        s2 += __expf(vt.z);
        s3 += __expf(vt.w);
    }
    float sum = (s0 + s1) + (s2 + s3);

    // ---- wave reduce, then block reduce across 16 waves ----
    #pragma unroll
    for (int off = 32; off > 0; off >>= 1)
        sum += __shfl_down(sum, off, 64);

    __shared__ float wsum[16];
    __shared__ float s_s[TT];
    __shared__ float es_s[TT];
    __shared__ float total_s;

    const int lane = tid & 63;
    const int wave = tid >> 6;
    if (lane == 0) wsum[wave] = sum;

    // ---- overlap: lanes of wave 1 gather tail scores while reduce settles ----
    const int L = tail_len[r];
    if (tid >= 64 && tid < 64 + TT) {
        const int j = tid - 64;
        float sv = 0.f, ev = 0.f;
        if (j < L) {
            sv = row[tails[r * TT + j]];
            ev = __expf(sv);
        }
        s_s[j]  = sv;
        es_s[j] = ev;
    }
    __syncthreads();

    if (tid == 0) {
        float t = 0.f;
        #pragma unroll
        for (int w = 0; w < 16; ++w) t += wsum[w];
        total_s = t;
    }
    __syncthreads();

    // ---- serial tail scan (T<=50) on thread 0 ----
    if (tid == 0) {
        const float total = total_s;
        const float ts = row[target[r]];
        const float log_pl = ts - __logf(total);

        float above = 0.f, sum_es = 0.f;
        for (int j = 0; j < L; ++j) {
            above  += s_s[j];
            sum_es += es_s[j];
        }
        const float others = total - __expf(ts) - sum_es;

        float run = 0.f, below = 0.f;
        for (int k = L - 1; k >= 0; --k) {
            run += es_s[k];
            below += __logf(run + others);
        }
        const float tail_term = (L > 0) ? (above - below) : 0.f;
        out[r] = -(log_pl + tail_term);
    }
}

extern "C" void kernel_launch(void* const* d_in, const int* in_sizes, int n_in,
                              void* d_out, int out_size, void* d_ws, size_t ws_size,
                              hipStream_t stream) {
    const float* output   = (const float*)d_in[0];
    const int*   target   = (const int*)d_in[1];
    const int*   tails    = (const int*)d_in[2];
    const int*   tail_len = (const int*)d_in[3];
    float*       out      = (float*)d_out;

    listmle_fused_kernel<<<BB, NTH, 0, stream>>>(output, target, tails, tail_len, out);
}